// Round 1
// baseline (353.591 us; speedup 1.0000x reference)
//
#include <hip/hip_runtime.h>

#define BATCH 2
#define NPT 6400
#define DD 32
#define FF 256
#define BS 128
#define NBINS 50
#define NHALF 25
#define NPTS (BATCH * NPT)   // 12800
#define NKEY 128             // keys range 0..98

__device__ __forceinline__ float elu_f(float x) {
    return x > 0.0f ? x : (__expf(x) - 1.0f);
}

// ---------------- K1: LSH bin keys ----------------
__global__ void k_binkey(const float* __restrict__ xd, const float* __restrict__ cb,
                         const int* __restrict__ msk, int* __restrict__ keys) {
    int g = blockIdx.x * blockDim.x + threadIdx.x;
    if (g >= NPTS) return;
    const float* xr = xd + (size_t)g * DD;
    float x[DD];
#pragma unroll
    for (int d = 0; d < DD; ++d) x[d] = xr[d];
    float mul[NHALF];
#pragma unroll
    for (int h = 0; h < NHALF; ++h) {
        float s = 0.f;
#pragma unroll
        for (int d = 0; d < DD; ++d) s = fmaf(x[d], cb[d * 100 + h], s);
        mul[h] = s;
    }
    // argmax over [mul[0..24], -mul[0..24]], first occurrence wins (strict >)
    float best = mul[0];
    int bi = 0;
#pragma unroll
    for (int h = 1; h < NHALF; ++h)
        if (mul[h] > best) { best = mul[h]; bi = h; }
#pragma unroll
    for (int h = 0; h < NHALF; ++h) {
        float v = -mul[h];
        if (v > best) { best = v; bi = NHALF + h; }
    }
    keys[g] = bi + (msk[g] != 0 ? 0 : (NBINS - 1));
}

// ---------------- K2: stable counting sort (argsort) ----------------
// 1 block per batch, 128 threads. Chunked stable counting sort: keys<=98.
__global__ void k_sort(const int* __restrict__ keys, float* __restrict__ bins_f,
                       int* __restrict__ bins_i) {
    __shared__ unsigned char sk[NPT];
    __shared__ unsigned short lh[NKEY][128];
    __shared__ int base[NKEY];
    int b = blockIdx.x;
    int t = threadIdx.x;  // 0..127
    for (int i = t; i < NPT; i += 128) sk[i] = (unsigned char)keys[b * NPT + i];
    for (int k = 0; k < NKEY; ++k) lh[k][t] = 0;
    __syncthreads();
    const int CH = NPT / 128;  // 50 elements per chunk, chunk t = [t*CH, t*CH+CH)
    int i0 = t * CH;
    for (int i = 0; i < CH; ++i) lh[sk[i0 + i]][t]++;  // column t private to thread t
    __syncthreads();
    // per-key exclusive prefix over chunks (thread t handles key t)
    {
        int run = 0;
        for (int c = 0; c < 128; ++c) {
            int v = lh[t][c];
            lh[t][c] = (unsigned short)run;
            run += v;
        }
        base[t] = run;  // total count of key t
    }
    __syncthreads();
    if (t == 0) {
        int run = 0;
        for (int k = 0; k < NKEY; ++k) {
            int v = base[k];
            base[k] = run;
            run += v;
        }
    }
    __syncthreads();
    // stable placement: chunks ascending, in-chunk ascending
    for (int i = 0; i < CH; ++i) {
        int idx = i0 + i;
        int k = sk[idx];
        int pos = base[k] + lh[k][t];
        lh[k][t] = (unsigned short)(lh[k][t] + 1);
        bins_f[b * NPT + pos] = (float)idx;
        bins_i[b * NPT + pos] = idx;
    }
}

// ---------------- K3: per-point A1/B1 precompute + mask gather ----------------
// A1 = x_dist_row @ W1[0:32,:], B1 = x_dist_row @ W1[32:64,:]
__global__ void k_points(const float* __restrict__ xd, const int* __restrict__ msk,
                         const int* __restrict__ bins_i, const float* __restrict__ W1,
                         float* __restrict__ a1b1, float* __restrict__ mws,
                         float* __restrict__ out_msk) {
    int g = blockIdx.x * blockDim.x + threadIdx.x;
    int p_lin = g >> 5;   // 0..12799
    int c = g & 31;
    if (p_lin >= NPTS) return;
    int bb = p_lin / NPT;
    int idx = bins_i[p_lin];
    const float* xr = xd + ((size_t)(bb * NPT + idx)) * DD;
    float a = 0.f, bv = 0.f;
#pragma unroll
    for (int d = 0; d < DD; ++d) {
        float xv = xr[d];
        a = fmaf(xv, W1[d * 32 + c], a);
        bv = fmaf(xv, W1[(DD + d) * 32 + c], bv);
    }
    a1b1[(size_t)p_lin * 64 + c] = a;
    a1b1[(size_t)p_lin * 64 + 32 + c] = bv;
    if (c == 0) {
        float m = (msk[bb * NPT + idx] != 0) ? 1.0f : 0.0f;
        mws[p_lin] = m;
        out_msk[p_lin] = m;
    }
}

// ---------------- K4: feature gather ----------------
__global__ void k_feat(const float* __restrict__ xf, const int* __restrict__ bins_i,
                       float* __restrict__ out_feat) {
    int g = blockIdx.x * blockDim.x + threadIdx.x;  // one float4 each
    if (g >= NPTS * (FF / 4)) return;
    int row = g >> 6;  // FF/4 = 64
    int q = g & 63;
    int bb = row / NPT;
    int idx = bins_i[row];
    const float4* src = (const float4*)(xf + ((size_t)(bb * NPT + idx)) * FF);
    float4* dst = (float4*)(out_feat + (size_t)row * FF);
    dst[q] = src[q];
}

// ---------------- K5: pairwise FFN ----------------
// block = 256 threads = 2 i-rows x 128 j. 64 blocks per (b,bin).
__global__ void __launch_bounds__(256) k_pairs(
    const float* __restrict__ a1b1, const float* __restrict__ mws,
    const float* __restrict__ b1, const float* __restrict__ W2,
    const float* __restrict__ b2, const float* __restrict__ W3,
    const float* __restrict__ b3, float* __restrict__ out_dm) {
    __shared__ float B1s[BS * 33];  // pad 33: bank=(j+k)%32, only free 2-way alias
    __shared__ float A1s[2 * 32];
    __shared__ float mjs[BS];
    __shared__ float mis[2];
    int t = threadIdx.x;
    int blk = blockIdx.x;
    int bin_lin = blk >> 6;   // 0..99  (= b*50+bin)
    int rowblk = blk & 63;
    int i0 = rowblk * 2;
    int base_p = bin_lin * BS;  // linear binned-point index base

    for (int idx = t; idx < BS * 32; idx += 256) {
        int r = idx >> 5, c = idx & 31;
        B1s[r * 33 + c] = a1b1[((size_t)(base_p + r)) * 64 + 32 + c];
    }
    if (t < 64) {
        int r = t >> 5, c = t & 31;
        A1s[r * 32 + c] = a1b1[((size_t)(base_p + i0 + r)) * 64 + c];
    }
    if (t < BS) mjs[t] = mws[base_p + t];
    if (t < 2) mis[t] = mws[base_p + i0 + t];
    __syncthreads();

    int j = t & 127;
    int ii = t >> 7;  // wave-uniform

    float h1[32], h2[32];
#pragma unroll
    for (int k = 0; k < 32; ++k)
        h1[k] = elu_f(A1s[ii * 32 + k] + B1s[j * 33 + k] + b1[k]);

#pragma unroll
    for (int c = 0; c < 32; ++c) h2[c] = b2[c];
#pragma unroll
    for (int k = 0; k < 32; ++k) {
        float hk = h1[k];
#pragma unroll
        for (int c = 0; c < 32; ++c) h2[c] = fmaf(hk, W2[k * 32 + c], h2[c]);
    }
#pragma unroll
    for (int c = 0; c < 32; ++c) h2[c] = elu_f(h2[c]);

    float h3[32];
#pragma unroll
    for (int c = 0; c < 32; ++c) h3[c] = b3[c];
#pragma unroll
    for (int k = 0; k < 32; ++k) {
        float hk = h2[k];
#pragma unroll
        for (int c = 0; c < 32; ++c) h3[c] = fmaf(hk, W3[k * 32 + c], h3[c]);
    }

    float m = mis[ii] * mjs[j];
#pragma unroll
    for (int c = 0; c < 32; ++c) h3[c] = elu_f(h3[c]) * m;

    size_t obase = ((((size_t)bin_lin * BS + (i0 + ii)) * BS) + j) * 32;
    float4* o4 = (float4*)(out_dm + obase);
#pragma unroll
    for (int q = 0; q < 8; ++q)
        o4[q] = make_float4(h3[4 * q], h3[4 * q + 1], h3[4 * q + 2], h3[4 * q + 3]);
}

extern "C" void kernel_launch(void* const* d_in, const int* in_sizes, int n_in,
                              void* d_out, int out_size, void* d_ws, size_t ws_size,
                              hipStream_t stream) {
    const float* xd  = (const float*)d_in[0];
    const float* xf  = (const float*)d_in[1];
    const int*   msk = (const int*)d_in[2];
    const float* cb  = (const float*)d_in[3];
    const float* W1  = (const float*)d_in[4];
    const float* b1  = (const float*)d_in[5];
    const float* W2  = (const float*)d_in[6];
    const float* b2  = (const float*)d_in[7];
    const float* W3  = (const float*)d_in[8];
    const float* b3  = (const float*)d_in[9];

    float* out = (float*)d_out;
    float* out_bins = out;                                        // 12800
    float* out_feat = out + 12800;                                // 3276800
    float* out_dm   = out + 12800 + 3276800;                      // 52428800
    float* out_msk  = out + 12800 + 3276800 + 52428800;           // 12800

    int*   keys   = (int*)d_ws;
    int*   bins_i = keys + NPTS;
    float* a1b1   = (float*)(bins_i + NPTS);
    float* mws    = a1b1 + (size_t)NPTS * 64;

    k_binkey<<<NPTS / 256, 256, 0, stream>>>(xd, cb, msk, keys);
    k_sort<<<BATCH, 128, 0, stream>>>(keys, out_bins, bins_i);
    k_points<<<NPTS * 32 / 256, 256, 0, stream>>>(xd, msk, bins_i, W1, a1b1, mws, out_msk);
    k_feat<<<NPTS * 64 / 256, 256, 0, stream>>>(xf, bins_i, out_feat);
    k_pairs<<<100 * 64, 256, 0, stream>>>(a1b1, mws, b1, W2, b2, W3, b3, out_dm);
}

// Round 2
// 289.916 us; speedup vs baseline: 1.2196x; 1.2196x over previous
//
#include <hip/hip_runtime.h>

#define BATCH 2
#define NPT 6400
#define DD 32
#define FF 256
#define BS 128
#define NBINS 50
#define NHALF 25
#define NPTS (BATCH * NPT)   // 12800
#define NKEY 100             // keys range 0..98
#define IST 8                // i-rows per k_pairs block

typedef __bf16 bf16x8 __attribute__((ext_vector_type(8)));
typedef float f32x4 __attribute__((ext_vector_type(4)));

__device__ __forceinline__ float elu_f(float x) {
    return x > 0.0f ? x : (__expf(x) - 1.0f);
}

// ---------------- K1: LSH bin keys ----------------
__global__ void k_binkey(const float* __restrict__ xd, const float* __restrict__ cb,
                         const int* __restrict__ msk, int* __restrict__ keys) {
    int g = blockIdx.x * blockDim.x + threadIdx.x;
    if (g >= NPTS) return;
    const float* xr = xd + (size_t)g * DD;
    float x[DD];
#pragma unroll
    for (int d = 0; d < DD; ++d) x[d] = xr[d];
    float mul[NHALF];
#pragma unroll
    for (int h = 0; h < NHALF; ++h) {
        float s = 0.f;
#pragma unroll
        for (int d = 0; d < DD; ++d) s = fmaf(x[d], cb[d * 100 + h], s);
        mul[h] = s;
    }
    float best = mul[0];
    int bi = 0;
#pragma unroll
    for (int h = 1; h < NHALF; ++h)
        if (mul[h] > best) { best = mul[h]; bi = h; }
#pragma unroll
    for (int h = 0; h < NHALF; ++h) {
        float v = -mul[h];
        if (v > best) { best = v; bi = NHALF + h; }
    }
    keys[g] = bi + (msk[g] != 0 ? 0 : (NBINS - 1));
}

// ---------------- K2: stable counting sort (argsort) ----------------
// 1 block per batch, 256 threads, 256 chunks of 25. Row stride 258 breaks the
// 64-way bank conflict (bank = t*129 + c/2 spreads across all 32 banks).
__global__ void k_sort(const int* __restrict__ keys, float* __restrict__ bins_f,
                       int* __restrict__ bins_i) {
    __shared__ unsigned char sk[NPT];
    __shared__ unsigned short lh[NKEY][258];
    __shared__ int base[128];
    int b = blockIdx.x;
    int t = threadIdx.x;  // 0..255
    for (int i = t; i < NPT; i += 256) sk[i] = (unsigned char)keys[b * NPT + i];
    for (int k = 0; k < NKEY; ++k) lh[k][t] = 0;
    __syncthreads();
    const int CH = NPT / 256;  // 25
    int i0 = t * CH;
#pragma unroll
    for (int i = 0; i < CH; ++i) lh[sk[i0 + i]][t]++;  // column t private
    __syncthreads();
    // per-key exclusive prefix over 256 chunks (thread t handles key t)
    int myrun = 0;
    if (t < NKEY) {
        int run = 0;
        for (int c = 0; c < 256; ++c) {
            int v = lh[t][c];
            lh[t][c] = (unsigned short)run;
            run += v;
        }
        myrun = run;
    }
    if (t < 128) base[t] = myrun;  // count of key t (0 for t>=NKEY)
    __syncthreads();
    // inclusive Hillis-Steele scan over base[0..127], then make exclusive
    for (int off = 1; off < 128; off <<= 1) {
        int v = (t < 128 && t >= off) ? base[t - off] : 0;
        __syncthreads();
        if (t < 128) base[t] += v;
        __syncthreads();
    }
    if (t < 128) base[t] -= myrun;  // exclusive
    __syncthreads();
    // stable placement: chunks ascending, in-chunk ascending
#pragma unroll
    for (int i = 0; i < CH; ++i) {
        int idx = i0 + i;
        int k = sk[idx];
        int pos = base[k] + lh[k][t];
        lh[k][t] = (unsigned short)(lh[k][t] + 1);
        bins_f[b * NPT + pos] = (float)idx;
        bins_i[b * NPT + pos] = idx;
    }
}

// ---------------- K3: per-point A1/B1 precompute (b1 folded into B1) ----------------
__global__ void k_points(const float* __restrict__ xd, const int* __restrict__ msk,
                         const int* __restrict__ bins_i, const float* __restrict__ W1,
                         const float* __restrict__ b1, float* __restrict__ a1b1,
                         float* __restrict__ mws, float* __restrict__ out_msk) {
    int g = blockIdx.x * blockDim.x + threadIdx.x;
    int p_lin = g >> 5;   // 0..12799
    int c = g & 31;
    if (p_lin >= NPTS) return;
    int bb = p_lin / NPT;
    int idx = bins_i[p_lin];
    const float* xr = xd + ((size_t)(bb * NPT + idx)) * DD;
    float a = 0.f, bv = b1[c];  // fold b1 into the B-side
#pragma unroll
    for (int d = 0; d < DD; ++d) {
        float xv = xr[d];
        a = fmaf(xv, W1[d * 32 + c], a);
        bv = fmaf(xv, W1[(DD + d) * 32 + c], bv);
    }
    a1b1[(size_t)p_lin * 64 + c] = a;
    a1b1[(size_t)p_lin * 64 + 32 + c] = bv;
    if (c == 0) {
        float m = (msk[bb * NPT + idx] != 0) ? 1.0f : 0.0f;
        mws[p_lin] = m;
        out_msk[p_lin] = m;
    }
}

// ---------------- K4: feature gather ----------------
__global__ void k_feat(const float* __restrict__ xf, const int* __restrict__ bins_i,
                       float* __restrict__ out_feat) {
    int g = blockIdx.x * blockDim.x + threadIdx.x;
    if (g >= NPTS * (FF / 4)) return;
    int row = g >> 6;
    int q = g & 63;
    int bb = row / NPT;
    int idx = bins_i[row];
    const float4* src = (const float4*)(xf + ((size_t)(bb * NPT + idx)) * FF);
    float4* dst = (float4*)(out_feat + (size_t)row * FF);
    dst[q] = src[q];
}

// ---------------- K5: pairwise FFN via MFMA ----------------
// Grid: 100 bins x 16 strips of 8 i-rows. Block 256 = 4 waves.
// Per wave-group of 16 pairs (i fixed, j0..j0+15):
//   h1 (A-layout, m=lane&15 -> j, k=quad*8+j) -> mfma x2 (W2 halves)
//   -> elu -> LDS scratch (C-layout write) -> A-layout read -> mfma x2 (W3)
//   -> elu * mask -> store.
__global__ void __launch_bounds__(256) k_pairs(
    const float* __restrict__ a1b1, const float* __restrict__ mws,
    const float* __restrict__ W2, const float* __restrict__ b2,
    const float* __restrict__ W3, const float* __restrict__ b3,
    float* __restrict__ out_dm) {
    __shared__ __attribute__((aligned(16))) float B1s[128][36];
    __shared__ __attribute__((aligned(16))) float A1s[IST][36];
    __shared__ float mjs[128];
    __shared__ float mis[IST];
    __shared__ __attribute__((aligned(16))) __bf16 scr[4][2][16 * 40];

    int t = threadIdx.x;
    int lane = t & 63;
    int wv = t >> 6;
    int n = lane & 15;
    int quad = lane >> 4;
    int koct = quad * 8;

    int bin = blockIdx.x >> 4;    // 0..99 (= b*50+bin)
    int strip = blockIdx.x & 15;  // 0..15
    int i_base = strip * IST;
    int base_p = bin * 128;

    for (int idx = t; idx < 128 * 8; idx += 256) {
        int r = idx >> 3, q = idx & 7;
        *(float4*)&B1s[r][q * 4] =
            *(const float4*)&a1b1[(size_t)(base_p + r) * 64 + 32 + q * 4];
    }
    if (t < IST * 8) {
        int r = t >> 3, q = t & 7;
        *(float4*)&A1s[r][q * 4] =
            *(const float4*)&a1b1[(size_t)(base_p + i_base + r) * 64 + q * 4];
    }
    if (t < 128) mjs[t] = mws[base_p + t];
    if (t < IST) mis[t] = mws[base_p + i_base + t];

    // constant weight fragments (B-layout: k=quad*8+j, col n / n+16)
    bf16x8 w2f0, w2f1, w3f0, w3f1;
#pragma unroll
    for (int j = 0; j < 8; ++j) {
        w2f0[j] = (__bf16)W2[(koct + j) * 32 + n];
        w2f1[j] = (__bf16)W2[(koct + j) * 32 + n + 16];
        w3f0[j] = (__bf16)W3[(koct + j) * 32 + n];
        w3f1[j] = (__bf16)W3[(koct + j) * 32 + n + 16];
    }
    float b2lo = b2[n], b2hi = b2[n + 16];
    float b3lo = b3[n], b3hi = b3[n + 16];
    __syncthreads();

    const f32x4 z = {0.f, 0.f, 0.f, 0.f};
    for (int g = 0; g < 16; ++g) {
        int grp = g * 4 + wv;      // 0..63
        int i_l = grp >> 3;
        int j0 = (grp & 7) * 16;

        float aA[8], bB[8];
        *(float4*)&aA[0] = *(float4*)&A1s[i_l][koct];
        *(float4*)&aA[4] = *(float4*)&A1s[i_l][koct + 4];
        *(float4*)&bB[0] = *(float4*)&B1s[j0 + n][koct];
        *(float4*)&bB[4] = *(float4*)&B1s[j0 + n][koct + 4];
        bf16x8 h1;
#pragma unroll
        for (int j = 0; j < 8; ++j) h1[j] = (__bf16)elu_f(aA[j] + bB[j]);

        f32x4 acc0 = __builtin_amdgcn_mfma_f32_16x16x32_bf16(h1, w2f0, z, 0, 0, 0);
        f32x4 acc1 = __builtin_amdgcn_mfma_f32_16x16x32_bf16(h1, w2f1, z, 0, 0, 0);

        // h2 -> scratch in C-layout (row = quad*4+r = pair, col = channel)
        __bf16* sc = &scr[wv][g & 1][0];
#pragma unroll
        for (int r = 0; r < 4; ++r) {
            sc[(quad * 4 + r) * 40 + n] = (__bf16)elu_f(acc0[r] + b2lo);
            sc[(quad * 4 + r) * 40 + n + 16] = (__bf16)elu_f(acc1[r] + b2hi);
        }
        __syncthreads();  // uniform trip count across all 4 waves

        // A-layout read: row m = lane&15 (pair), k = koct..koct+7
        bf16x8 h2 = *(bf16x8*)&sc[n * 40 + koct];
        f32x4 acc2 = __builtin_amdgcn_mfma_f32_16x16x32_bf16(h2, w3f0, z, 0, 0, 0);
        f32x4 acc3 = __builtin_amdgcn_mfma_f32_16x16x32_bf16(h2, w3f1, z, 0, 0, 0);

        float miv = mis[i_l];
        size_t obase = ((size_t)(bin * 128 + i_base + i_l) * 128 + j0) * 32;
#pragma unroll
        for (int r = 0; r < 4; ++r) {
            int jr = quad * 4 + r;
            float mm = miv * mjs[j0 + jr];
            out_dm[obase + (size_t)jr * 32 + n] = elu_f(acc2[r] + b3lo) * mm;
            out_dm[obase + (size_t)jr * 32 + n + 16] = elu_f(acc3[r] + b3hi) * mm;
        }
    }
}

extern "C" void kernel_launch(void* const* d_in, const int* in_sizes, int n_in,
                              void* d_out, int out_size, void* d_ws, size_t ws_size,
                              hipStream_t stream) {
    const float* xd  = (const float*)d_in[0];
    const float* xf  = (const float*)d_in[1];
    const int*   msk = (const int*)d_in[2];
    const float* cb  = (const float*)d_in[3];
    const float* W1  = (const float*)d_in[4];
    const float* b1  = (const float*)d_in[5];
    const float* W2  = (const float*)d_in[6];
    const float* b2  = (const float*)d_in[7];
    const float* W3  = (const float*)d_in[8];
    const float* b3  = (const float*)d_in[9];

    float* out = (float*)d_out;
    float* out_bins = out;                                        // 12800
    float* out_feat = out + 12800;                                // 3276800
    float* out_dm   = out + 12800 + 3276800;                      // 52428800
    float* out_msk  = out + 12800 + 3276800 + 52428800;           // 12800

    int*   keys   = (int*)d_ws;
    int*   bins_i = keys + NPTS;
    float* a1b1   = (float*)(bins_i + NPTS);
    float* mws    = a1b1 + (size_t)NPTS * 64;

    k_binkey<<<NPTS / 256, 256, 0, stream>>>(xd, cb, msk, keys);
    k_sort<<<BATCH, 256, 0, stream>>>(keys, out_bins, bins_i);
    k_points<<<NPTS * 32 / 256, 256, 0, stream>>>(xd, msk, bins_i, W1, b1, a1b1, mws, out_msk);
    k_feat<<<NPTS * 64 / 256, 256, 0, stream>>>(xf, bins_i, out_feat);
    k_pairs<<<100 * 16, 256, 0, stream>>>(a1b1, mws, W2, b2, W3, b3, out_dm);
}

// Round 3
// 286.914 us; speedup vs baseline: 1.2324x; 1.0105x over previous
//
#include <hip/hip_runtime.h>

#define BATCH 2
#define NPT 6400
#define DD 32
#define FF 256
#define BS 128
#define NBINS 50
#define NHALF 25
#define NPTS (BATCH * NPT)   // 12800
#define NKEY 100             // keys range 0..98
#define IST 8                // i-rows per k_pairs block

typedef __bf16 bf16x8 __attribute__((ext_vector_type(8)));
typedef float f32x4 __attribute__((ext_vector_type(4)));

__device__ __forceinline__ float elu_f(float x) {
    return x > 0.0f ? x : (__expf(x) - 1.0f);
}

// ---------------- K1: LSH bin keys ----------------
__global__ void k_binkey(const float* __restrict__ xd, const float* __restrict__ cb,
                         const int* __restrict__ msk, int* __restrict__ keys) {
    int g = blockIdx.x * blockDim.x + threadIdx.x;
    if (g >= NPTS) return;
    const float* xr = xd + (size_t)g * DD;
    float x[DD];
#pragma unroll
    for (int d = 0; d < DD; ++d) x[d] = xr[d];
    float mul[NHALF];
#pragma unroll
    for (int h = 0; h < NHALF; ++h) {
        float s = 0.f;
#pragma unroll
        for (int d = 0; d < DD; ++d) s = fmaf(x[d], cb[d * 100 + h], s);
        mul[h] = s;
    }
    float best = mul[0];
    int bi = 0;
#pragma unroll
    for (int h = 1; h < NHALF; ++h)
        if (mul[h] > best) { best = mul[h]; bi = h; }
#pragma unroll
    for (int h = 0; h < NHALF; ++h) {
        float v = -mul[h];
        if (v > best) { best = v; bi = NHALF + h; }
    }
    keys[g] = bi + (msk[g] != 0 ? 0 : (NBINS - 1));
}

// ---------------- K2: stable counting sort (argsort) ----------------
__global__ void k_sort(const int* __restrict__ keys, float* __restrict__ bins_f,
                       int* __restrict__ bins_i) {
    __shared__ unsigned char sk[NPT];
    __shared__ unsigned short lh[NKEY][258];
    __shared__ int base[128];
    int b = blockIdx.x;
    int t = threadIdx.x;  // 0..255
    for (int i = t; i < NPT; i += 256) sk[i] = (unsigned char)keys[b * NPT + i];
    for (int k = 0; k < NKEY; ++k) lh[k][t] = 0;
    __syncthreads();
    const int CH = NPT / 256;  // 25
    int i0 = t * CH;
#pragma unroll
    for (int i = 0; i < CH; ++i) lh[sk[i0 + i]][t]++;  // column t private
    __syncthreads();
    int myrun = 0;
    if (t < NKEY) {
        int run = 0;
        for (int c = 0; c < 256; ++c) {
            int v = lh[t][c];
            lh[t][c] = (unsigned short)run;
            run += v;
        }
        myrun = run;
    }
    if (t < 128) base[t] = myrun;
    __syncthreads();
    for (int off = 1; off < 128; off <<= 1) {
        int v = (t < 128 && t >= off) ? base[t - off] : 0;
        __syncthreads();
        if (t < 128) base[t] += v;
        __syncthreads();
    }
    if (t < 128) base[t] -= myrun;  // exclusive
    __syncthreads();
#pragma unroll
    for (int i = 0; i < CH; ++i) {
        int idx = i0 + i;
        int k = sk[idx];
        int pos = base[k] + lh[k][t];
        lh[k][t] = (unsigned short)(lh[k][t] + 1);
        bins_f[b * NPT + pos] = (float)idx;
        bins_i[b * NPT + pos] = idx;
    }
}

// ---------------- K3: fused gather: features + A1/B1 + masks ----------------
// One wave per binned point. Lanes 0..63: copy 1KB feature row (float4 each);
// same lanes compute the 64 A1|B1 columns; lane 0 writes masks.
__global__ void __launch_bounds__(256) k_gather(
    const float* __restrict__ xd, const float* __restrict__ xf,
    const int* __restrict__ msk, const int* __restrict__ bins_i,
    const float* __restrict__ W1, const float* __restrict__ b1,
    float* __restrict__ out_feat, float* __restrict__ a1b1,
    float* __restrict__ mws, float* __restrict__ out_msk) {
    int t = threadIdx.x;
    int wv = t >> 6;
    int l = t & 63;
    int p_lin = blockIdx.x * 4 + wv;  // 0..12799
    if (p_lin >= NPTS) return;
    int bb = p_lin / NPT;
    int idx = bins_i[p_lin];
    int src_row = bb * NPT + idx;

    // feature row copy: 64 lanes x float4 = 256 floats
    const float4* src = (const float4*)(xf + (size_t)src_row * FF);
    float4* dst = (float4*)(out_feat + (size_t)p_lin * FF);
    dst[l] = src[l];

    // A1/B1: lane l<32 -> A col l; lane l>=32 -> B col l-32 (b1 folded)
    const float* xr = xd + (size_t)src_row * DD;
    int c = l & 31;
    int side = l >> 5;
    float acc = side ? b1[c] : 0.f;
    const float* Wcol = W1 + (size_t)side * DD * 32;
#pragma unroll
    for (int d = 0; d < DD; ++d) acc = fmaf(xr[d], Wcol[d * 32 + c], acc);
    a1b1[(size_t)p_lin * 64 + l] = acc;

    if (l == 0) {
        float m = (msk[src_row] != 0) ? 1.0f : 0.0f;
        mws[p_lin] = m;
        out_msk[p_lin] = m;
    }
}

// ---------------- K4: pairwise FFN via MFMA ----------------
// Grid: 100 bins x 16 strips of IST=8 i-rows. Block 256 = 4 waves.
// No per-iteration barrier: scr transpose scratch is wave-private; DS pipe
// is in-order per wave, compiler handles lgkmcnt.
__global__ void __launch_bounds__(256) k_pairs(
    const float* __restrict__ a1b1, const float* __restrict__ mws,
    const float* __restrict__ W2, const float* __restrict__ b2,
    const float* __restrict__ W3, const float* __restrict__ b3,
    float* __restrict__ out_dm) {
    __shared__ __attribute__((aligned(16))) float B1s[128][36];
    __shared__ __attribute__((aligned(16))) float A1s[IST][36];
    __shared__ float mjs[128];
    __shared__ float mis[IST];
    __shared__ __attribute__((aligned(16))) __bf16 scr[4][16 * 40];

    int t = threadIdx.x;
    int lane = t & 63;
    int wv = t >> 6;
    int n = lane & 15;
    int quad = lane >> 4;
    int koct = quad * 8;

    int bin = blockIdx.x >> 4;    // 0..99 (= b*50+bin)
    int strip = blockIdx.x & 15;  // 0..15
    int i_base = strip * IST;
    int base_p = bin * 128;

    for (int idx = t; idx < 128 * 8; idx += 256) {
        int r = idx >> 3, q = idx & 7;
        *(float4*)&B1s[r][q * 4] =
            *(const float4*)&a1b1[(size_t)(base_p + r) * 64 + 32 + q * 4];
    }
    if (t < IST * 8) {
        int r = t >> 3, q = t & 7;
        *(float4*)&A1s[r][q * 4] =
            *(const float4*)&a1b1[(size_t)(base_p + i_base + r) * 64 + q * 4];
    }
    if (t < 128) mjs[t] = mws[base_p + t];
    if (t < IST) mis[t] = mws[base_p + i_base + t];

    // constant weight fragments (B-layout: k=koct+j, col n / n+16)
    bf16x8 w2f0, w2f1, w3f0, w3f1;
#pragma unroll
    for (int j = 0; j < 8; ++j) {
        w2f0[j] = (__bf16)W2[(koct + j) * 32 + n];
        w2f1[j] = (__bf16)W2[(koct + j) * 32 + n + 16];
        w3f0[j] = (__bf16)W3[(koct + j) * 32 + n];
        w3f1[j] = (__bf16)W3[(koct + j) * 32 + n + 16];
    }
    float b2lo = b2[n], b2hi = b2[n + 16];
    float b3lo = b3[n], b3hi = b3[n + 16];
    __syncthreads();  // staging barrier (cross-wave) — the only one

    const f32x4 z = {0.f, 0.f, 0.f, 0.f};
    __bf16* sc = &scr[wv][0];
    for (int g = 0; g < 16; ++g) {
        int grp = g * 4 + wv;      // 0..63
        int i_l = grp >> 3;
        int j0 = (grp & 7) * 16;

        float aA[8], bB[8];
        *(float4*)&aA[0] = *(float4*)&A1s[i_l][koct];
        *(float4*)&aA[4] = *(float4*)&A1s[i_l][koct + 4];
        *(float4*)&bB[0] = *(float4*)&B1s[j0 + n][koct];
        *(float4*)&bB[4] = *(float4*)&B1s[j0 + n][koct + 4];
        bf16x8 h1;
#pragma unroll
        for (int j = 0; j < 8; ++j) h1[j] = (__bf16)elu_f(aA[j] + bB[j]);

        f32x4 acc0 = __builtin_amdgcn_mfma_f32_16x16x32_bf16(h1, w2f0, z, 0, 0, 0);
        f32x4 acc1 = __builtin_amdgcn_mfma_f32_16x16x32_bf16(h1, w2f1, z, 0, 0, 0);

        // h2 -> wave-private scratch in C-layout (row = quad*4+r, col)
#pragma unroll
        for (int r = 0; r < 4; ++r) {
            sc[(quad * 4 + r) * 40 + n] = (__bf16)elu_f(acc0[r] + b2lo);
            sc[(quad * 4 + r) * 40 + n + 16] = (__bf16)elu_f(acc1[r] + b2hi);
        }
        // A-layout read back: row m = n (pair), k = koct..koct+7
        bf16x8 h2 = *(bf16x8*)&sc[n * 40 + koct];
        f32x4 acc2 = __builtin_amdgcn_mfma_f32_16x16x32_bf16(h2, w3f0, z, 0, 0, 0);
        f32x4 acc3 = __builtin_amdgcn_mfma_f32_16x16x32_bf16(h2, w3f1, z, 0, 0, 0);

        float miv = mis[i_l];
        size_t obase = ((size_t)(bin * 128 + i_base + i_l) * 128 + j0) * 32;
#pragma unroll
        for (int r = 0; r < 4; ++r) {
            int jr = quad * 4 + r;
            float mm = miv * mjs[j0 + jr];
            out_dm[obase + (size_t)jr * 32 + n] = elu_f(acc2[r] + b3lo) * mm;
            out_dm[obase + (size_t)jr * 32 + n + 16] = elu_f(acc3[r] + b3hi) * mm;
        }
    }
}

extern "C" void kernel_launch(void* const* d_in, const int* in_sizes, int n_in,
                              void* d_out, int out_size, void* d_ws, size_t ws_size,
                              hipStream_t stream) {
    const float* xd  = (const float*)d_in[0];
    const float* xf  = (const float*)d_in[1];
    const int*   msk = (const int*)d_in[2];
    const float* cb  = (const float*)d_in[3];
    const float* W1  = (const float*)d_in[4];
    const float* b1  = (const float*)d_in[5];
    const float* W2  = (const float*)d_in[6];
    const float* b2  = (const float*)d_in[7];
    const float* W3  = (const float*)d_in[8];
    const float* b3  = (const float*)d_in[9];

    float* out = (float*)d_out;
    float* out_bins = out;                                        // 12800
    float* out_feat = out + 12800;                                // 3276800
    float* out_dm   = out + 12800 + 3276800;                      // 52428800
    float* out_msk  = out + 12800 + 3276800 + 52428800;           // 12800

    int*   keys   = (int*)d_ws;
    int*   bins_i = keys + NPTS;
    float* a1b1   = (float*)(bins_i + NPTS);
    float* mws    = a1b1 + (size_t)NPTS * 64;

    k_binkey<<<NPTS / 256, 256, 0, stream>>>(xd, cb, msk, keys);
    k_sort<<<BATCH, 256, 0, stream>>>(keys, out_bins, bins_i);
    k_gather<<<NPTS / 4, 256, 0, stream>>>(xd, xf, msk, bins_i, W1, b1,
                                           out_feat, a1b1, mws, out_msk);
    k_pairs<<<100 * 16, 256, 0, stream>>>(a1b1, mws, W2, b2, W3, b3, out_dm);
}

// Round 4
// 280.821 us; speedup vs baseline: 1.2591x; 1.0217x over previous
//
#include <hip/hip_runtime.h>

#define BATCH 2
#define NPT 6400
#define DD 32
#define FF 256
#define BS 128
#define NBINS 50
#define NHALF 25
#define NPTS (BATCH * NPT)   // 12800
#define NKEY 100             // keys range 0..98
#define IST 8                // i-rows per k_pairs block

typedef __bf16 bf16x8 __attribute__((ext_vector_type(8)));
typedef float f32x4 __attribute__((ext_vector_type(4)));

__device__ __forceinline__ float elu_f(float x) {
    return x > 0.0f ? x : (__expf(x) - 1.0f);
}

// ---------------- K1: LSH bin keys ----------------
__global__ void k_binkey(const float* __restrict__ xd, const float* __restrict__ cb,
                         const int* __restrict__ msk, int* __restrict__ keys) {
    int g = blockIdx.x * blockDim.x + threadIdx.x;
    if (g >= NPTS) return;
    const float4* xr4 = (const float4*)(xd + (size_t)g * DD);
    float x[DD];
#pragma unroll
    for (int q = 0; q < DD / 4; ++q) *(float4*)&x[q * 4] = xr4[q];
    float mul[NHALF];
#pragma unroll
    for (int h = 0; h < NHALF; ++h) {
        float s = 0.f;
#pragma unroll
        for (int d = 0; d < DD; ++d) s = fmaf(x[d], cb[d * 100 + h], s);
        mul[h] = s;
    }
    float best = mul[0];
    int bi = 0;
#pragma unroll
    for (int h = 1; h < NHALF; ++h)
        if (mul[h] > best) { best = mul[h]; bi = h; }
#pragma unroll
    for (int h = 0; h < NHALF; ++h) {
        float v = -mul[h];
        if (v > best) { best = v; bi = NHALF + h; }
    }
    keys[g] = bi + (msk[g] != 0 ? 0 : (NBINS - 1));
}

// ---------------- K2: stable counting sort (argsort) ----------------
// bins_i only; the float copy (output 0) is emitted coalesced by k_gather.
__global__ void k_sort(const int* __restrict__ keys, int* __restrict__ bins_i) {
    __shared__ unsigned char sk[NPT];
    __shared__ unsigned short lh[NKEY][258];
    __shared__ int base[128];
    int b = blockIdx.x;
    int t = threadIdx.x;  // 0..255
    for (int i = t; i < NPT; i += 256) sk[i] = (unsigned char)keys[b * NPT + i];
    for (int k = 0; k < NKEY; ++k) lh[k][t] = 0;
    __syncthreads();
    const int CH = NPT / 256;  // 25
    int i0 = t * CH;
#pragma unroll
    for (int i = 0; i < CH; ++i) lh[sk[i0 + i]][t]++;  // column t private
    __syncthreads();
    int myrun = 0;
    if (t < NKEY) {
        int run = 0;
        for (int c = 0; c < 256; ++c) {
            int v = lh[t][c];
            lh[t][c] = (unsigned short)run;
            run += v;
        }
        myrun = run;
    }
    if (t < 128) base[t] = myrun;
    __syncthreads();
    for (int off = 1; off < 128; off <<= 1) {
        int v = (t < 128 && t >= off) ? base[t - off] : 0;
        __syncthreads();
        if (t < 128) base[t] += v;
        __syncthreads();
    }
    if (t < 128) base[t] -= myrun;  // exclusive
    __syncthreads();
#pragma unroll
    for (int i = 0; i < CH; ++i) {
        int idx = i0 + i;
        int k = sk[idx];
        int pos = base[k] + lh[k][t];
        lh[k][t] = (unsigned short)(lh[k][t] + 1);
        bins_i[b * NPT + pos] = idx;
    }
}

// ---------------- K3: fused gather: features + A1/B1 + masks + bins_f ----------------
__global__ void __launch_bounds__(256) k_gather(
    const float* __restrict__ xd, const float* __restrict__ xf,
    const int* __restrict__ msk, const int* __restrict__ bins_i,
    const float* __restrict__ W1, const float* __restrict__ b1,
    float* __restrict__ out_bins, float* __restrict__ out_feat,
    float* __restrict__ a1b1, float* __restrict__ mws,
    float* __restrict__ out_msk) {
    int t = threadIdx.x;
    int wv = t >> 6;
    int l = t & 63;
    int p_lin = blockIdx.x * 4 + wv;  // 0..12799
    if (p_lin >= NPTS) return;
    int bb = p_lin / NPT;
    int idx = bins_i[p_lin];
    int src_row = bb * NPT + idx;

    // feature row copy: 64 lanes x float4 = 256 floats
    const float4* src = (const float4*)(xf + (size_t)src_row * FF);
    float4* dst = (float4*)(out_feat + (size_t)p_lin * FF);
    dst[l] = src[l];

    // A1/B1: lane l<32 -> A col l; lane l>=32 -> B col l-32 (b1 folded)
    const float* xr = xd + (size_t)src_row * DD;
    int c = l & 31;
    int side = l >> 5;
    float acc = side ? b1[c] : 0.f;
    const float* Wcol = W1 + (size_t)side * DD * 32;
#pragma unroll
    for (int d = 0; d < DD; ++d) acc = fmaf(xr[d], Wcol[d * 32 + c], acc);
    a1b1[(size_t)p_lin * 64 + l] = acc;

    if (l == 0) {
        float m = (msk[src_row] != 0) ? 1.0f : 0.0f;
        mws[p_lin] = m;
        out_msk[p_lin] = m;
        out_bins[p_lin] = (float)idx;
    }
}

// ---------------- K4: pairwise FFN via MFMA ----------------
// Grid: 100 bins x 16 strips of IST=8 i-rows. Block 256 = 4 waves.
// scr double-buffered by g parity (wave-private) + unroll 2 so the compiler
// can prove DS non-alias and interleave consecutive g-chains. No per-g barrier.
__global__ void __launch_bounds__(256) k_pairs(
    const float* __restrict__ a1b1, const float* __restrict__ mws,
    const float* __restrict__ W2, const float* __restrict__ b2,
    const float* __restrict__ W3, const float* __restrict__ b3,
    float* __restrict__ out_dm) {
    __shared__ __attribute__((aligned(16))) float B1s[128][36];
    __shared__ __attribute__((aligned(16))) float A1s[IST][36];
    __shared__ float mjs[128];
    __shared__ float mis[IST];
    __shared__ __attribute__((aligned(16))) __bf16 scr[4][2][16 * 40];

    int t = threadIdx.x;
    int lane = t & 63;
    int wv = t >> 6;
    int n = lane & 15;
    int quad = lane >> 4;
    int koct = quad * 8;

    int bin = blockIdx.x >> 4;    // 0..99 (= b*50+bin)
    int strip = blockIdx.x & 15;  // 0..15
    int i_base = strip * IST;
    int base_p = bin * 128;

    for (int idx = t; idx < 128 * 8; idx += 256) {
        int r = idx >> 3, q = idx & 7;
        *(float4*)&B1s[r][q * 4] =
            *(const float4*)&a1b1[(size_t)(base_p + r) * 64 + 32 + q * 4];
    }
    if (t < IST * 8) {
        int r = t >> 3, q = t & 7;
        *(float4*)&A1s[r][q * 4] =
            *(const float4*)&a1b1[(size_t)(base_p + i_base + r) * 64 + q * 4];
    }
    if (t < 128) mjs[t] = mws[base_p + t];
    if (t < IST) mis[t] = mws[base_p + i_base + t];

    // constant weight fragments (B-layout: k=koct+j, col n / n+16)
    bf16x8 w2f0, w2f1, w3f0, w3f1;
#pragma unroll
    for (int j = 0; j < 8; ++j) {
        w2f0[j] = (__bf16)W2[(koct + j) * 32 + n];
        w2f1[j] = (__bf16)W2[(koct + j) * 32 + n + 16];
        w3f0[j] = (__bf16)W3[(koct + j) * 32 + n];
        w3f1[j] = (__bf16)W3[(koct + j) * 32 + n + 16];
    }
    float b2lo = b2[n], b2hi = b2[n + 16];
    float b3lo = b3[n], b3hi = b3[n + 16];
    __syncthreads();  // staging barrier — the only one

    const f32x4 z = {0.f, 0.f, 0.f, 0.f};
#pragma unroll 2
    for (int g = 0; g < 16; ++g) {
        int grp = g * 4 + wv;      // 0..63
        int i_l = grp >> 3;
        int j0 = (grp & 7) * 16;

        float aA[8], bB[8];
        *(float4*)&aA[0] = *(float4*)&A1s[i_l][koct];
        *(float4*)&aA[4] = *(float4*)&A1s[i_l][koct + 4];
        *(float4*)&bB[0] = *(float4*)&B1s[j0 + n][koct];
        *(float4*)&bB[4] = *(float4*)&B1s[j0 + n][koct + 4];
        bf16x8 h1;
#pragma unroll
        for (int j = 0; j < 8; ++j) h1[j] = (__bf16)elu_f(aA[j] + bB[j]);

        f32x4 acc0 = __builtin_amdgcn_mfma_f32_16x16x32_bf16(h1, w2f0, z, 0, 0, 0);
        f32x4 acc1 = __builtin_amdgcn_mfma_f32_16x16x32_bf16(h1, w2f1, z, 0, 0, 0);

        // h2 -> wave-private parity scratch in C-layout (row = quad*4+r, col)
        __bf16* sc = &scr[wv][g & 1][0];
#pragma unroll
        for (int r = 0; r < 4; ++r) {
            sc[(quad * 4 + r) * 40 + n] = (__bf16)elu_f(acc0[r] + b2lo);
            sc[(quad * 4 + r) * 40 + n + 16] = (__bf16)elu_f(acc1[r] + b2hi);
        }
        // A-layout read back: row m = n (pair), k = koct..koct+7
        bf16x8 h2 = *(bf16x8*)&sc[n * 40 + koct];
        f32x4 acc2 = __builtin_amdgcn_mfma_f32_16x16x32_bf16(h2, w3f0, z, 0, 0, 0);
        f32x4 acc3 = __builtin_amdgcn_mfma_f32_16x16x32_bf16(h2, w3f1, z, 0, 0, 0);

        float miv = mis[i_l];
        size_t obase = ((size_t)(bin * 128 + i_base + i_l) * 128 + j0) * 32;
#pragma unroll
        for (int r = 0; r < 4; ++r) {
            int jr = quad * 4 + r;
            float mm = miv * mjs[j0 + jr];
            out_dm[obase + (size_t)jr * 32 + n] = elu_f(acc2[r] + b3lo) * mm;
            out_dm[obase + (size_t)jr * 32 + n + 16] = elu_f(acc3[r] + b3hi) * mm;
        }
    }
}

extern "C" void kernel_launch(void* const* d_in, const int* in_sizes, int n_in,
                              void* d_out, int out_size, void* d_ws, size_t ws_size,
                              hipStream_t stream) {
    const float* xd  = (const float*)d_in[0];
    const float* xf  = (const float*)d_in[1];
    const int*   msk = (const int*)d_in[2];
    const float* cb  = (const float*)d_in[3];
    const float* W1  = (const float*)d_in[4];
    const float* b1  = (const float*)d_in[5];
    const float* W2  = (const float*)d_in[6];
    const float* b2  = (const float*)d_in[7];
    const float* W3  = (const float*)d_in[8];
    const float* b3  = (const float*)d_in[9];

    float* out = (float*)d_out;
    float* out_bins = out;                                        // 12800
    float* out_feat = out + 12800;                                // 3276800
    float* out_dm   = out + 12800 + 3276800;                      // 52428800
    float* out_msk  = out + 12800 + 3276800 + 52428800;           // 12800

    int*   keys   = (int*)d_ws;
    int*   bins_i = keys + NPTS;
    float* a1b1   = (float*)(bins_i + NPTS);
    float* mws    = a1b1 + (size_t)NPTS * 64;

    k_binkey<<<NPTS / 256, 256, 0, stream>>>(xd, cb, msk, keys);
    k_sort<<<BATCH, 256, 0, stream>>>(keys, bins_i);
    k_gather<<<NPTS / 4, 256, 0, stream>>>(xd, xf, msk, bins_i, W1, b1,
                                           out_bins, out_feat, a1b1, mws, out_msk);
    k_pairs<<<100 * 16, 256, 0, stream>>>(a1b1, mws, W2, b2, W3, b3, out_dm);
}